// Round 1
// baseline (8189.227 us; speedup 1.0000x reference)
//
#include <hip/hip_runtime.h>
#include <hip/hip_bf16.h>

// Problem constants
#define NB   32      // batch
#define HH   1024    // hidden
#define LL   512     // seq len
#define KTOT 2048    // 2*H (cat = [short, now])
#define CH   256     // K-chunk staged in LDS
#define WSTR 2056    // weight LDS row stride (bf16 elems; +8 keeps 16B align, breaks bank conflicts)
#define CSTR 264     // cat LDS row stride    (256+8)

typedef __bf16 bf8 __attribute__((ext_vector_type(8)));
typedef float  f4  __attribute__((ext_vector_type(4)));
typedef unsigned short us8 __attribute__((ext_vector_type(8)));

__device__ __forceinline__ unsigned short f2bf(float f) {
  unsigned u = __builtin_bit_cast(unsigned, f);
  u += 0x7fffu + ((u >> 16) & 1u);           // RNE
  return (unsigned short)(u >> 16);
}

__device__ __forceinline__ void waitflag(unsigned* p, unsigned tgt) {
  if (threadIdx.x == 0) {
    while (__hip_atomic_load(p, __ATOMIC_ACQUIRE, __HIP_MEMORY_SCOPE_AGENT) < tgt)
      __builtin_amdgcn_s_sleep(1);
  }
  __syncthreads();
}

// 256 WGs x 256 threads, persistent. WG w: layer = w>>7, owns hidden units
// h0..h0+7 (h0 = (w&127)*8) -> 32 W rows (4 gates x 8 h), full K=2048 in LDS (bf16).
__global__ void __launch_bounds__(256, 1)
lstm_persist(const int* __restrict__ tokens, const float* __restrict__ emb,
             const float* __restrict__ W, const float* __restrict__ Bb,
             float* __restrict__ out, unsigned* flags, unsigned short* s1)
{
  __shared__ unsigned short wlds[32 * WSTR];   // 131,584 B  weights bf16, resident all steps
  __shared__ unsigned short cat [32 * CSTR];   //  16,896 B  staged input chunk [32 n][256 k]
  __shared__ float glds[32 * 36];              //   4,608 B  gate scatter
  __shared__ float bias[32];

  const int tid   = threadIdx.x;
  const int layer = blockIdx.x >> 7;
  const int h0    = (blockIdx.x & 127) * 8;
  unsigned* cnt1  = flags;         // layer-1 step completion counters [512]
  unsigned* cnt2  = flags + 512;   // layer-2
  unsigned* mycnt = layer ? cnt2 : cnt1;

  // ---- one-time: load W slice (32 rows x 2048 fp32) -> bf16 LDS ----
  for (int it = 0; it < 32; ++it) {
    int e = (it * 256 + tid) * 8;              // element index 0..65535
    int r = e >> 11;                           // local row 0..31  (g = r>>3, i = r&7)
    int k = e & 2047;
    const float* src = W + (((size_t)layer * 4 + (r >> 3)) * HH + (h0 + (r & 7))) * (size_t)KTOT + k;
    f4 a = *(const f4*)src;
    f4 b = *(const f4*)(src + 4);
    us8 v;
    v[0]=f2bf(a[0]); v[1]=f2bf(a[1]); v[2]=f2bf(a[2]); v[3]=f2bf(a[3]);
    v[4]=f2bf(b[0]); v[5]=f2bf(b[1]); v[6]=f2bf(b[2]); v[7]=f2bf(b[3]);
    *(us8*)&wlds[r * WSTR + k] = v;
  }
  if (tid < 32) bias[tid] = Bb[((size_t)layer * 4 + (tid >> 3)) * HH + h0 + (tid & 7)];
  __syncthreads();

  // MFMA tiling: 4 waves = 2(n) x 2(j) tiles of 16x16, K chunked by 256
  const int lane = tid & 63;
  const int wid  = tid >> 6;
  const int nh = wid >> 1, jh = wid & 1;
  const unsigned short* ap0 = &cat [(nh * 16 + (lane & 15)) * CSTR + ((lane >> 4) * 8)];
  const unsigned short* bp0 = &wlds[(jh * 16 + (lane & 15)) * WSTR + ((lane >> 4) * 8)];
  const int sn  = tid >> 3;          // staging row (batch n)
  const int skc = (tid & 7) * 32;    // staging col within chunk

  float lng = 0.f;                   // cell state for (n=sn, h=h0+(tid&7)) — lives here forever
  us8 v0, v1, v2, v3;

  auto packA = [&](f4 a, f4 b) {
    us8 r;
    r[0]=f2bf(a[0]); r[1]=f2bf(a[1]); r[2]=f2bf(a[2]); r[3]=f2bf(a[3]);
    r[4]=f2bf(b[0]); r[5]=f2bf(b[1]); r[6]=f2bf(b[2]); r[7]=f2bf(b[3]);
    return r;
  };
  auto loadBF16 = [&](const unsigned short* p) {
    v0 = *(const us8*)(p + 0);  v1 = *(const us8*)(p + 8);
    v2 = *(const us8*)(p + 16); v3 = *(const us8*)(p + 24);
  };
  auto loadF32 = [&](const float* p) {
    v0 = packA(*(const f4*)(p + 0),  *(const f4*)(p + 4));
    v1 = packA(*(const f4*)(p + 8),  *(const f4*)(p + 12));
    v2 = packA(*(const f4*)(p + 16), *(const f4*)(p + 20));
    v3 = packA(*(const f4*)(p + 24), *(const f4*)(p + 28));
  };

  for (int t = 0; t < LL; ++t) {
    f4 acc = {0.f, 0.f, 0.f, 0.f};

    auto loadNow = [&](int c) {          // chunks 4..7: k = 1024 + (c-4)*256  ("now")
      int off = (c - 4) * CH + skc;
      if (layer == 0) {
        int tok = tokens[sn * LL + t];
        loadF32(emb + (size_t)tok * HH + off);
      } else {
        loadBF16(s1 + ((size_t)(t + 1) * NB + sn) * HH + off);   // layer-1 output at t
      }
    };
    auto loadPrev = [&](int c) {         // chunks 0..3: k = c*256  (recurrent short)
      int off = c * CH + skc;
      if (layer == 0) {
        loadBF16(s1 + ((size_t)t * NB + sn) * HH + off);         // s1[0] is zeroed
      } else {
        if (t == 0) { v0 = 0; v1 = 0; v2 = 0; v3 = 0; }
        else loadF32(out + ((size_t)sn * LL + (t - 1)) * HH + off);
      }
    };
    auto stageStore = [&]() {
      *(us8*)&cat[sn * CSTR + skc +  0] = v0;
      *(us8*)&cat[sn * CSTR + skc +  8] = v1;
      *(us8*)&cat[sn * CSTR + skc + 16] = v2;
      *(us8*)&cat[sn * CSTR + skc + 24] = v3;
    };
    auto compute = [&](int c) {
      const unsigned short* ap = ap0;
      const unsigned short* bp = bp0 + c * CH;
      #pragma unroll
      for (int m = 0; m < 8; ++m) {
        bf8 a = __builtin_bit_cast(bf8, *(const us8*)(ap + m * 32));
        bf8 b = __builtin_bit_cast(bf8, *(const us8*)(bp + m * 32));
        acc = __builtin_amdgcn_mfma_f32_16x16x32_bf16(a, b, acc, 0, 0, 0);
      }
    };

    // ---- "now" half first (hides spin latency of the recurrent flag) ----
    if (layer == 1) waitflag(cnt1 + t, 128);         // need layer-1 output at t
    loadNow(4);
    for (int c = 4; c < 8; ++c) {
      __syncthreads();
      stageStore();
      if (c < 7) loadNow(c + 1);
      __syncthreads();
      compute(c);
    }
    // ---- recurrent half ----
    if (t > 0) waitflag(mycnt + (t - 1), 128);       // own layer's previous step
    loadPrev(0);
    for (int c = 0; c < 4; ++c) {
      __syncthreads();
      stageStore();
      if (c < 3) loadPrev(c + 1);
      __syncthreads();
      compute(c);
    }

    // ---- scatter gates to LDS (C/D layout: col=lane&15, row=(lane>>4)*4+reg) ----
    __syncthreads();
    {
      int grow = nh * 16 + (lane >> 4) * 4;
      int gcol = jh * 16 + (lane & 15);
      glds[(grow + 0) * 36 + gcol] = acc[0];
      glds[(grow + 1) * 36 + gcol] = acc[1];
      glds[(grow + 2) * 36 + gcol] = acc[2];
      glds[(grow + 3) * 36 + gcol] = acc[3];
    }
    __syncthreads();

    // ---- state update: thread owns (n=sn, i=tid&7); gate order f,i,o,cand (cand RAW) ----
    {
      int i = tid & 7;
      float gf = glds[sn * 36 +  0 + i] + bias[ 0 + i];
      float gi = glds[sn * 36 +  8 + i] + bias[ 8 + i];
      float go = glds[sn * 36 + 16 + i] + bias[16 + i];
      float gc = glds[sn * 36 + 24 + i] + bias[24 + i];
      float fg = 1.f / (1.f + expf(-gf));
      float ig = 1.f / (1.f + expf(-gi));
      float og = 1.f / (1.f + expf(-go));
      lng = fg * lng + ig * gc;                       // NOTE: no tanh on cand (matches ref)
      float sh = og * tanhf(lng);
      if (layer == 0)
        s1[((size_t)(t + 1) * NB + sn) * HH + h0 + i] = f2bf(sh);
      else
        out[((size_t)sn * LL + t) * HH + h0 + i] = sh;
    }
    __syncthreads();   // drain all global stores (s_waitcnt vmcnt(0) per wave) before release
    if (tid == 0)
      __hip_atomic_fetch_add(mycnt + t, 1u, __ATOMIC_RELEASE, __HIP_MEMORY_SCOPE_AGENT);
  }
}

extern "C" void kernel_launch(void* const* d_in, const int* in_sizes, int n_in,
                              void* d_out, int out_size, void* d_ws, size_t ws_size,
                              hipStream_t stream) {
  const int*   tokens = (const int*)d_in[0];
  const float* emb    = (const float*)d_in[1];
  const float* W      = (const float*)d_in[2];
  const float* Bb     = (const float*)d_in[3];
  float*       out    = (float*)d_out;

  // ws layout: [0,4KB) cnt1|cnt2 flags, [8KB, 8KB+513*64KB) short1 bf16 history [t+1][n][h]
  unsigned*       flags = (unsigned*)d_ws;
  unsigned short* s1    = (unsigned short*)((char*)d_ws + 8192);

  // zero flags + short1 step-0 state (captured into the graph -> re-run every replay)
  hipMemsetAsync(d_ws, 0, 8192 + (size_t)NB * HH * sizeof(unsigned short), stream);

  void* args[] = { (void*)&tokens, (void*)&emb, (void*)&W, (void*)&Bb,
                   (void*)&out, (void*)&flags, (void*)&s1 };
  hipLaunchCooperativeKernel((void*)lstm_persist, dim3(256), dim3(256), args, 0, stream);
}

// Round 5
// 7730.665 us; speedup vs baseline: 1.0593x; 1.0593x over previous
//
#include <hip/hip_runtime.h>
#include <hip/hip_bf16.h>

#define NB   32
#define HH   1024
#define LL   512
#define KTOT 2048

typedef __bf16 bf8 __attribute__((ext_vector_type(8)));
typedef float  f4  __attribute__((ext_vector_type(4)));
typedef unsigned short us8 __attribute__((ext_vector_type(8)));

// Software round-to-nearest-even f32 -> bf16 (K1-proven numerics)
__device__ __forceinline__ unsigned short f2bf(float f) {
  unsigned u = __builtin_bit_cast(unsigned, f);
  u += 0x7fffu + ((u >> 16) & 1u);
  return (unsigned short)(u >> 16);
}
__device__ __forceinline__ us8 pack8(f4 a, f4 b) {
  us8 r;
  r[0]=f2bf(a[0]); r[1]=f2bf(a[1]); r[2]=f2bf(a[2]); r[3]=f2bf(a[3]);
  r[4]=f2bf(b[0]); r[5]=f2bf(b[1]); r[6]=f2bf(b[2]); r[7]=f2bf(b[3]);
  return r;
}

// K1-proven sync: tid0 ACQUIRE spin, then block barrier. Plain loads after.
__device__ __forceinline__ void waitflag(unsigned* p, unsigned tgt) {
  if (threadIdx.x == 0) {
    while (__hip_atomic_load(p, __ATOMIC_ACQUIRE, __HIP_MEMORY_SCOPE_AGENT) < tgt)
      __builtin_amdgcn_s_sleep(1);
  }
  __syncthreads();
}

// ---- optional pre-pass (only if ws_size allows): x0[t][n][h] = bf16(emb[tokens]) ----
__global__ void __launch_bounds__(256)
prepack(const int* __restrict__ tokens, const float* __restrict__ emb,
        unsigned short* __restrict__ x0) {
  int idx = blockIdx.x * 256 + threadIdx.x;     // 32*512*128 = 2,097,152
  int n  = idx >> 16;
  int t  = (idx >> 7) & 511;
  int h  = (idx & 127) << 3;
  int row = tokens[n * LL + t];
  const float* src = emb + (size_t)row * HH + h;
  *(us8*)(x0 + ((size_t)t * NB + n) * HH + h) = pack8(*(const f4*)src, *(const f4*)(src + 4));
}

// ---- persistent dataflow LSTM: 256 WGs x 256 thr; WG w: layer=w>>7, h-octet w&127 ----
// Sync = K1 verbatim: plain data stores -> __syncthreads (vmcnt drained per wave)
// -> tid0 RELEASE fetch_add on cnt[t]. Consumer: tid0 ACQUIRE spin -> __syncthreads
// -> plain cached data loads (acquire's invalidate makes them fetch fresh).
__global__ void __launch_bounds__(256, 1)
lstm_persist(const int* __restrict__ tokens, const float* __restrict__ emb,
             const float* __restrict__ W, const float* __restrict__ Bb,
             float* __restrict__ out, unsigned* flags, unsigned short* s1,
             unsigned short* s2, const unsigned short* x0)
{
  // wlds fragment order: slot(jh, cm, lane) = jh*4096 + cm*64 + lane (8 bf16 each):
  // holds W row j = jh*16+(lane&15), k = cm*32 + (lane>>4)*8 .. +8
  // -> every ds_read_b128 is lane-linear (zero bank conflicts)
  __shared__ unsigned short wlds[65536];   // 128 KiB
  __shared__ float glds[32 * 36];
  __shared__ float bias[32];

  const int tid   = threadIdx.x;
  const int layer = blockIdx.x >> 7;
  const int h0    = (blockIdx.x & 127) * 8;
  unsigned* cnt1  = flags;         // layer-0 per-step completion counters [512]
  unsigned* cnt2  = flags + 512;   // layer-1
  unsigned* mycnt = layer ? cnt2 : cnt1;

  // one-time: W slice (32 rows x 2048 f32, coalesced reads) -> fragment-ordered bf16 LDS
  for (int it = 0; it < 32; ++it) {
    int e = (it * 256 + tid) * 8;
    int r = e >> 11;                       // local row: gate = r>>3, i = r&7 ; MFMA col j == r
    int k = e & 2047;
    const float* src = W + (((size_t)layer * 4 + (r >> 3)) * HH + (h0 + (r & 7))) * (size_t)KTOT + k;
    int slot = ((r >> 4) << 12) + (((k >> 8) * 8 + ((k >> 5) & 7)) << 6) + (r & 15) + (((k >> 3) & 3) << 4);
    *(us8*)&wlds[(unsigned)slot * 8] = pack8(*(const f4*)src, *(const f4*)(src + 4));
  }
  if (tid < 32) bias[tid] = Bb[((size_t)layer * 4 + (tid >> 3)) * HH + h0 + (tid & 7)];
  __syncthreads();

  const int lane = tid & 63;
  const int wid  = tid >> 6;
  const int nh = wid >> 1, jh = wid & 1;
  const int arow  = nh * 16 + (lane & 15);     // batch row for A fragments
  const int rbase = (lane >> 4) * 8;           // k-slice within 32-wide K step
  const unsigned short* wbase = &wlds[((unsigned)(jh * 4096 + lane)) * 8u];

  float lng = 0.f;                             // cell state (n=tid>>3, h=h0+(tid&7))

  for (int t = 0; t < LL; ++t) {
    us8 nf[4][8], rf[4][8];
    f4 acc = {0.f, 0.f, 0.f, 0.f};

    // ---------- "now" half (flag-free for layer 0; cnt1[t] for layer 1) ----------
    if (layer == 0) {
      if (x0) {
        const unsigned short* nsrc = x0 + ((size_t)t * NB + arow) * HH + rbase;
        #pragma unroll
        for (int c = 0; c < 4; ++c)
          #pragma unroll
          for (int m = 0; m < 8; ++m)
            nf[c][m] = *(const us8*)(nsrc + c * 256 + m * 32);
      } else {
        const float* nsrc = emb + (size_t)tokens[arow * LL + t] * HH + rbase;
        #pragma unroll
        for (int c = 0; c < 4; ++c)
          #pragma unroll
          for (int m = 0; m < 8; ++m)
            nf[c][m] = pack8(*(const f4*)(nsrc + c * 256 + m * 32),
                             *(const f4*)(nsrc + c * 256 + m * 32 + 4));
      }
    } else {
      waitflag(cnt1 + t, 128);
      const unsigned short* nsrc = s1 + ((size_t)t * NB + arow) * HH + rbase;
      #pragma unroll
      for (int c = 0; c < 4; ++c)
        #pragma unroll
        for (int m = 0; m < 8; ++m)
          nf[c][m] = *(const us8*)(nsrc + c * 256 + m * 32);
    }
    #pragma unroll
    for (int c = 0; c < 4; ++c)
      #pragma unroll
      for (int m = 0; m < 8; ++m)
        acc = __builtin_amdgcn_mfma_f32_16x16x32_bf16(
                __builtin_bit_cast(bf8, nf[c][m]),
                __builtin_bit_cast(bf8, *(const us8*)(wbase + ((4 + c) * 8 + m) * 512)),
                acc, 0, 0, 0);

    // ---------- recurrent half (own layer's previous step) ----------
    if (t > 0) {
      waitflag(mycnt + (t - 1), 128);
      if (layer == 0) {
        const unsigned short* rsrc = s1 + ((size_t)(t - 1) * NB + arow) * HH + rbase;
        #pragma unroll
        for (int c = 0; c < 4; ++c)
          #pragma unroll
          for (int m = 0; m < 8; ++m)
            rf[c][m] = *(const us8*)(rsrc + c * 256 + m * 32);
      } else if (s2) {
        const unsigned short* rsrc = s2 + ((size_t)(t - 1) * NB + arow) * HH + rbase;
        #pragma unroll
        for (int c = 0; c < 4; ++c)
          #pragma unroll
          for (int m = 0; m < 8; ++m)
            rf[c][m] = *(const us8*)(rsrc + c * 256 + m * 32);
      } else {
        const float* rsrc = out + ((size_t)arow * LL + (t - 1)) * HH + rbase;
        #pragma unroll
        for (int c = 0; c < 4; ++c)
          #pragma unroll
          for (int m = 0; m < 8; ++m)
            rf[c][m] = pack8(*(const f4*)(rsrc + c * 256 + m * 32),
                             *(const f4*)(rsrc + c * 256 + m * 32 + 4));
      }
      #pragma unroll
      for (int c = 0; c < 4; ++c)
        #pragma unroll
        for (int m = 0; m < 8; ++m)
          acc = __builtin_amdgcn_mfma_f32_16x16x32_bf16(
                  __builtin_bit_cast(bf8, rf[c][m]),
                  __builtin_bit_cast(bf8, *(const us8*)(wbase + (c * 8 + m) * 512)),
                  acc, 0, 0, 0);
    }

    // ---------- scatter gates (C/D: col=lane&15, row=(lane>>4)*4+reg) ----------
    {
      int grow = nh * 16 + ((lane >> 4) << 2);
      int gcol = jh * 16 + (lane & 15);
      glds[(grow + 0) * 36 + gcol] = acc[0];
      glds[(grow + 1) * 36 + gcol] = acc[1];
      glds[(grow + 2) * 36 + gcol] = acc[2];
      glds[(grow + 3) * 36 + gcol] = acc[3];
    }
    __syncthreads();

    // ---------- state update: thread owns (n=tid>>3, i=tid&7); gates f,i,o,cand ----------
    {
      int n = tid >> 3, i = tid & 7;
      float gf = glds[n * 36 +  0 + i] + bias[ 0 + i];
      float gi = glds[n * 36 +  8 + i] + bias[ 8 + i];
      float go = glds[n * 36 + 16 + i] + bias[16 + i];
      float gc = glds[n * 36 + 24 + i] + bias[24 + i];
      float fg = 1.f / (1.f + __expf(-gf));
      float ig = 1.f / (1.f + __expf(-gi));
      float og = 1.f / (1.f + __expf(-go));
      lng = fg * lng + ig * gc;                     // cand raw (matches reference)
      float a  = fabsf(lng);
      float e  = __expf(-2.f * a);
      float th = __builtin_copysignf((1.f - e) / (1.f + e), lng);
      float sh = og * th;
      if (layer == 0) {
        s1[((size_t)t * NB + n) * HH + h0 + i] = f2bf(sh);
      } else {
        out[((size_t)n * LL + t) * HH + h0 + i] = sh;
        if (s2) s2[((size_t)t * NB + n) * HH + h0 + i] = f2bf(sh);
      }
    }
    __syncthreads();   // every wave drains vmcnt(0) at this barrier -> stores in L2
    if (tid == 0)
      __hip_atomic_fetch_add(mycnt + t, 1u, __ATOMIC_RELEASE, __HIP_MEMORY_SCOPE_AGENT);
  }
}

extern "C" void kernel_launch(void* const* d_in, const int* in_sizes, int n_in,
                              void* d_out, int out_size, void* d_ws, size_t ws_size,
                              hipStream_t stream) {
  const int*   tokens = (const int*)d_in[0];
  const float* emb    = (const float*)d_in[1];
  const float* W      = (const float*)d_in[2];
  const float* Bb     = (const float*)d_in[3];
  float*       out    = (float*)d_out;

  // ws layout (each region enabled only if ws_size proves it fits; K1 proved >= 33.6MB):
  //   [0, 8KB)                      flags: cnt1[512] | cnt2[512]
  //   [8KB, +32MB)                  s1 bf16 [512][32][1024]          (required)
  //   [8KB+32MB, +32MB)             s2 bf16 (layer-1 state, optional)
  //   [8KB+64MB, +32MB)             x0 bf16 (prepacked emb, optional)
  const size_t SZ = (size_t)LL * NB * HH * sizeof(unsigned short);   // 33,554,432
  unsigned*       flags = (unsigned*)d_ws;
  unsigned short* s1    = (unsigned short*)((char*)d_ws + 8192);
  unsigned short* s2    = (ws_size >= 8192 + 2 * SZ) ? (unsigned short*)((char*)d_ws + 8192 + SZ) : nullptr;
  unsigned short* x0    = (ws_size >= 8192 + 3 * SZ) ? (unsigned short*)((char*)d_ws + 8192 + 2 * SZ) : nullptr;

  hipMemsetAsync(d_ws, 0, 8192, stream);   // zero flags every replay (graph-captured)
  if (x0) prepack<<<dim3(8192), dim3(256), 0, stream>>>(tokens, emb, x0);

  void* args[] = { (void*)&tokens, (void*)&emb, (void*)&W, (void*)&Bb,
                   (void*)&out, (void*)&flags, (void*)&s1, (void*)&s2, (void*)&x0 };
  hipLaunchCooperativeKernel((void*)lstm_persist, dim3(256), dim3(256), args, 0, stream);
}

// Round 8
// 7277.061 us; speedup vs baseline: 1.1253x; 1.0623x over previous
//
#include <hip/hip_runtime.h>
#include <hip/hip_bf16.h>

#define NB   32
#define HH   1024
#define LL   512
#define KTOT 2048

typedef __bf16 bf8 __attribute__((ext_vector_type(8)));
typedef float  f4  __attribute__((ext_vector_type(4)));
typedef unsigned short us8 __attribute__((ext_vector_type(8)));

// Software round-to-nearest-even f32 -> bf16 (R1/R5-proven numerics)
__device__ __forceinline__ unsigned short f2bf(float f) {
  unsigned u = __builtin_bit_cast(unsigned, f);
  u += 0x7fffu + ((u >> 16) & 1u);
  return (unsigned short)(u >> 16);
}
__device__ __forceinline__ us8 pack8(f4 a, f4 b) {
  us8 r;
  r[0]=f2bf(a[0]); r[1]=f2bf(a[1]); r[2]=f2bf(a[2]); r[3]=f2bf(a[3]);
  r[4]=f2bf(b[0]); r[5]=f2bf(b[1]); r[6]=f2bf(b[2]); r[7]=f2bf(b[3]);
  return r;
}

// FROZEN sync primitive (R1/R5-proven), widened to 8 sub-counters:
// lanes 0..7 each ACQUIRE-spin on their own 64B line, then block barrier.
// Same per-thread primitive as R5's tid0 spin; the acquire's cache
// invalidate is cache-wide, so after the barrier plain loads are fresh.
__device__ __forceinline__ void waitsubs(unsigned* base, unsigned tgt) {
  if (threadIdx.x < 8) {
    unsigned* p = base + threadIdx.x * 16;        // 16 dwords = 64B stride
    while (__hip_atomic_load(p, __ATOMIC_ACQUIRE, __HIP_MEMORY_SCOPE_AGENT) < tgt)
      __builtin_amdgcn_s_sleep(32);               // ~2048cy backoff: cut inv-poll rate
  }
  __syncthreads();
}

// ---- optional pre-pass (only if ws_size allows): x0[t][n][h] = bf16(emb[tokens]) ----
__global__ void __launch_bounds__(256)
prepack(const int* __restrict__ tokens, const float* __restrict__ emb,
        unsigned short* __restrict__ x0) {
  int idx = blockIdx.x * 256 + threadIdx.x;     // 32*512*128 = 2,097,152
  int n  = idx >> 16;
  int t  = (idx >> 7) & 511;
  int h  = (idx & 127) << 3;
  int row = tokens[n * LL + t];
  const float* src = emb + (size_t)row * HH + h;
  *(us8*)(x0 + ((size_t)t * NB + n) * HH + h) = pack8(*(const f4*)src, *(const f4*)(src + 4));
}

// ---- persistent dataflow LSTM: 256 WGs x 256 thr (R5 geometry, the only
// passing structure). WG w: layer=w>>7, h-octet w&127.
// Producer: plain stores -> __syncthreads (vmcnt drained) -> tid0 RELEASE
// fetch_add on sub-counter (wg&7), 16 producers/line instead of 128/line.
__global__ void __launch_bounds__(256, 1)
lstm_persist(const int* __restrict__ tokens, const float* __restrict__ emb,
             const float* __restrict__ W, const float* __restrict__ Bb,
             float* __restrict__ out, unsigned* flags, unsigned short* s1,
             unsigned short* s2, const unsigned short* x0)
{
  // wlds fragment order: slot(jh, cm, lane) = jh*4096 + cm*64 + lane (8 bf16 each):
  // holds W row j = jh*16+(lane&15), k = cm*32 + (lane>>4)*8 .. +8
  // -> every ds_read_b128 is lane-linear (zero bank conflicts)
  __shared__ unsigned short wlds[65536];   // 128 KiB
  __shared__ float glds[32 * 36];
  __shared__ float bias[32];

  const int tid   = threadIdx.x;
  const int layer = blockIdx.x >> 7;
  const int wg    = blockIdx.x & 127;
  const int h0    = wg * 8;
  // sub-counter layout: cnt[layer][t][sub] , sub-stride 16 dwords (64B line)
  unsigned* cnt1  = flags;                  // layer-0: 512 steps x 8 subs x 16
  unsigned* cnt2  = flags + 512 * 128;      // layer-1
  unsigned* mycnt = layer ? cnt2 : cnt1;
  const int mysub = (wg & 7) * 16;

  // one-time: W slice (32 rows x 2048 f32, coalesced reads) -> fragment-ordered bf16 LDS
  for (int it = 0; it < 32; ++it) {
    int e = (it * 256 + tid) * 8;
    int r = e >> 11;                       // local row: gate = r>>3, i = r&7
    int k = e & 2047;
    const float* src = W + (((size_t)layer * 4 + (r >> 3)) * HH + (h0 + (r & 7))) * (size_t)KTOT + k;
    int slot = ((r >> 4) << 12) + (((k >> 8) * 8 + ((k >> 5) & 7)) << 6) + (r & 15) + (((k >> 3) & 3) << 4);
    *(us8*)&wlds[(unsigned)slot * 8] = pack8(*(const f4*)src, *(const f4*)(src + 4));
  }
  if (tid < 32) bias[tid] = Bb[((size_t)layer * 4 + (tid >> 3)) * HH + h0 + (tid & 7)];
  __syncthreads();

  const int lane = tid & 63;
  const int wid  = tid >> 6;
  const int nh = wid >> 1, jh = wid & 1;
  const int arow  = nh * 16 + (lane & 15);     // batch row for A fragments
  const int rbase = (lane >> 4) * 8;           // k-slice within 32-wide K step
  const unsigned short* wbase = &wlds[((unsigned)(jh * 4096 + lane)) * 8u];

  float lng = 0.f;                             // cell state (n=tid>>3, h=h0+(tid&7))

  for (int t = 0; t < LL; ++t) {
    us8 nf[4][8], rf[4][8];
    f4 acc = {0.f, 0.f, 0.f, 0.f};

    // ---------- "now" half (flag-free for layer 0; cnt1[t] for layer 1) ----------
    if (layer == 0) {
      if (x0) {
        const unsigned short* nsrc = x0 + ((size_t)t * NB + arow) * HH + rbase;
        #pragma unroll
        for (int c = 0; c < 4; ++c)
          #pragma unroll
          for (int m = 0; m < 8; ++m)
            nf[c][m] = *(const us8*)(nsrc + c * 256 + m * 32);
      } else {
        const float* nsrc = emb + (size_t)tokens[arow * LL + t] * HH + rbase;
        #pragma unroll
        for (int c = 0; c < 4; ++c)
          #pragma unroll
          for (int m = 0; m < 8; ++m)
            nf[c][m] = pack8(*(const f4*)(nsrc + c * 256 + m * 32),
                             *(const f4*)(nsrc + c * 256 + m * 32 + 4));
      }
    } else {
      waitsubs(cnt1 + (size_t)t * 128, 16);
      const unsigned short* nsrc = s1 + ((size_t)t * NB + arow) * HH + rbase;
      #pragma unroll
      for (int c = 0; c < 4; ++c)
        #pragma unroll
        for (int m = 0; m < 8; ++m)
          nf[c][m] = *(const us8*)(nsrc + c * 256 + m * 32);
    }
    #pragma unroll
    for (int c = 0; c < 4; ++c)
      #pragma unroll
      for (int m = 0; m < 8; ++m)
        acc = __builtin_amdgcn_mfma_f32_16x16x32_bf16(
                __builtin_bit_cast(bf8, nf[c][m]),
                __builtin_bit_cast(bf8, *(const us8*)(wbase + ((4 + c) * 8 + m) * 512)),
                acc, 0, 0, 0);

    // ---------- recurrent half (own layer's previous step) ----------
    if (t > 0) {
      waitsubs(mycnt + (size_t)(t - 1) * 128, 16);
      if (layer == 0) {
        const unsigned short* rsrc = s1 + ((size_t)(t - 1) * NB + arow) * HH + rbase;
        #pragma unroll
        for (int c = 0; c < 4; ++c)
          #pragma unroll
          for (int m = 0; m < 8; ++m)
            rf[c][m] = *(const us8*)(rsrc + c * 256 + m * 32);
      } else if (s2) {
        const unsigned short* rsrc = s2 + ((size_t)(t - 1) * NB + arow) * HH + rbase;
        #pragma unroll
        for (int c = 0; c < 4; ++c)
          #pragma unroll
          for (int m = 0; m < 8; ++m)
            rf[c][m] = *(const us8*)(rsrc + c * 256 + m * 32);
      } else {
        const float* rsrc = out + ((size_t)arow * LL + (t - 1)) * HH + rbase;
        #pragma unroll
        for (int c = 0; c < 4; ++c)
          #pragma unroll
          for (int m = 0; m < 8; ++m)
            rf[c][m] = pack8(*(const f4*)(rsrc + c * 256 + m * 32),
                             *(const f4*)(rsrc + c * 256 + m * 32 + 4));
      }
      #pragma unroll
      for (int c = 0; c < 4; ++c)
        #pragma unroll
        for (int m = 0; m < 8; ++m)
          acc = __builtin_amdgcn_mfma_f32_16x16x32_bf16(
                  __builtin_bit_cast(bf8, rf[c][m]),
                  __builtin_bit_cast(bf8, *(const us8*)(wbase + (c * 8 + m) * 512)),
                  acc, 0, 0, 0);
    }

    // ---------- scatter gates (C/D: col=lane&15, row=(lane>>4)*4+reg) ----------
    {
      int grow = nh * 16 + ((lane >> 4) << 2);
      int gcol = jh * 16 + (lane & 15);
      glds[(grow + 0) * 36 + gcol] = acc[0];
      glds[(grow + 1) * 36 + gcol] = acc[1];
      glds[(grow + 2) * 36 + gcol] = acc[2];
      glds[(grow + 3) * 36 + gcol] = acc[3];
    }
    __syncthreads();

    // ---------- state update: thread owns (n=tid>>3, i=tid&7); gates f,i,o,cand ----------
    {
      int n = tid >> 3, i = tid & 7;
      float gf = glds[n * 36 +  0 + i] + bias[ 0 + i];
      float gi = glds[n * 36 +  8 + i] + bias[ 8 + i];
      float go = glds[n * 36 + 16 + i] + bias[16 + i];
      float gc = glds[n * 36 + 24 + i] + bias[24 + i];
      float fg = 1.f / (1.f + __expf(-gf));
      float ig = 1.f / (1.f + __expf(-gi));
      float og = 1.f / (1.f + __expf(-go));
      lng = fg * lng + ig * gc;                     // cand raw (matches reference)
      float a  = fabsf(lng);
      float e  = __expf(-2.f * a);
      float th = __builtin_copysignf((1.f - e) / (1.f + e), lng);
      float sh = og * th;
      if (layer == 0) {
        s1[((size_t)t * NB + n) * HH + h0 + i] = f2bf(sh);
      } else {
        out[((size_t)n * LL + t) * HH + h0 + i] = sh;
        if (s2) s2[((size_t)t * NB + n) * HH + h0 + i] = f2bf(sh);
      }
    }
    __syncthreads();   // every wave drains vmcnt(0) at this barrier -> stores in L2
    if (tid == 0)
      __hip_atomic_fetch_add(mycnt + (size_t)t * 128 + mysub, 1u,
                             __ATOMIC_RELEASE, __HIP_MEMORY_SCOPE_AGENT);
  }
}

extern "C" void kernel_launch(void* const* d_in, const int* in_sizes, int n_in,
                              void* d_out, int out_size, void* d_ws, size_t ws_size,
                              hipStream_t stream) {
  const int*   tokens = (const int*)d_in[0];
  const float* emb    = (const float*)d_in[1];
  const float* W      = (const float*)d_in[2];
  const float* Bb     = (const float*)d_in[3];
  float*       out    = (float*)d_out;

  // ws layout:
  //   [0, 512KB)   sub-counters: cnt[2][512][8] on separate 64B lines
  //   [512KB,+32MB) s1 bf16 [512][32][1024]                    (required)
  //   optional s2 (layer-1 bf16 state), optional x0 (prepacked emb)
  const size_t FL = 524288;
  const size_t SZ = (size_t)LL * NB * HH * sizeof(unsigned short);   // 32 MiB
  unsigned*       flags = (unsigned*)d_ws;
  unsigned short* s1    = (unsigned short*)((char*)d_ws + FL);
  unsigned short* s2    = (ws_size >= FL + 2 * SZ) ? (unsigned short*)((char*)d_ws + FL + SZ) : nullptr;
  unsigned short* x0    = (ws_size >= FL + 3 * SZ) ? (unsigned short*)((char*)d_ws + FL + 2 * SZ) : nullptr;

  hipMemsetAsync(d_ws, 0, FL, stream);   // zero counters every replay (graph-captured)
  if (x0) prepack<<<dim3(8192), dim3(256), 0, stream>>>(tokens, emb, x0);

  void* args[] = { (void*)&tokens, (void*)&emb, (void*)&W, (void*)&Bb,
                   (void*)&out, (void*)&flags, (void*)&s1, (void*)&s2, (void*)&x0 };
  hipLaunchCooperativeKernel((void*)lstm_persist, dim3(256), dim3(256), args, 0, stream);
}

// Round 9
// 6485.589 us; speedup vs baseline: 1.2627x; 1.1220x over previous
//
#include <hip/hip_runtime.h>
#include <hip/hip_bf16.h>

#define NB   32
#define HH   1024
#define LL   512
#define KTOT 2048

typedef __bf16 bf8 __attribute__((ext_vector_type(8)));
typedef float  f4  __attribute__((ext_vector_type(4)));
typedef unsigned short us8 __attribute__((ext_vector_type(8)));

// Software round-to-nearest-even f32 -> bf16 (R1/R5/R8-proven numerics)
__device__ __forceinline__ unsigned short f2bf(float f) {
  unsigned u = __builtin_bit_cast(unsigned, f);
  u += 0x7fffu + ((u >> 16) & 1u);
  return (unsigned short)(u >> 16);
}
__device__ __forceinline__ us8 pack8(f4 a, f4 b) {
  us8 r;
  r[0]=f2bf(a[0]); r[1]=f2bf(a[1]); r[2]=f2bf(a[2]); r[3]=f2bf(a[3]);
  r[4]=f2bf(b[0]); r[5]=f2bf(b[1]); r[6]=f2bf(b[2]); r[7]=f2bf(b[3]);
  return r;
}

// FROZEN sync primitive (R1/R5/R8-proven): lanes 0..7 ACQUIRE-spin on their own
// 64B sub-counter line, then block barrier; plain data loads after.
__device__ __forceinline__ void waitsubs(unsigned* base, unsigned tgt) {
  if (threadIdx.x < 8) {
    unsigned* p = base + threadIdx.x * 16;        // 16 dwords = 64B stride
    while (__hip_atomic_load(p, __ATOMIC_ACQUIRE, __HIP_MEMORY_SCOPE_AGENT) < tgt)
      __builtin_amdgcn_s_sleep(8);                // ~512cy backoff
  }
  __syncthreads();
}

// Write-through data store (H1 test): agent-scope relaxed atomic store goes to
// the coherence point, leaving no dirty L2 line for the release's wbl2 to walk.
__device__ __forceinline__ void stwt(unsigned* p, unsigned v) {
  __hip_atomic_store(p, v, __ATOMIC_RELAXED, __HIP_MEMORY_SCOPE_AGENT);
}

// ---- optional pre-pass (only if ws_size allows): x0[t][n][h] = bf16(emb[tokens]) ----
__global__ void __launch_bounds__(256)
prepack(const int* __restrict__ tokens, const float* __restrict__ emb,
        unsigned short* __restrict__ x0) {
  int idx = blockIdx.x * 256 + threadIdx.x;     // 32*512*128 = 2,097,152
  int n  = idx >> 16;
  int t  = (idx >> 7) & 511;
  int h  = (idx & 127) << 3;
  int row = tokens[n * LL + t];
  const float* src = emb + (size_t)row * HH + h;
  *(us8*)(x0 + ((size_t)t * NB + n) * HH + h) = pack8(*(const f4*)src, *(const f4*)(src + 4));
}

// ---- persistent dataflow LSTM: 256 WGs x 256 thr (R5/R8 geometry — the only
// passing structure). WG w: layer=w>>7, h-octet w&127.
// Producer: WRITE-THROUGH data stores -> __syncthreads (vmcnt drained) ->
// tid0 RELEASE fetch_add on sub-counter (wg&7). Consumer: frozen waitsubs ->
// plain loads (post-inv, fetch fresh from the coherence point).
__global__ void __launch_bounds__(256, 1)
lstm_persist(const int* __restrict__ tokens, const float* __restrict__ emb,
             const float* __restrict__ W, const float* __restrict__ Bb,
             float* __restrict__ out, unsigned* flags, unsigned short* s1,
             unsigned short* s2, const unsigned short* x0)
{
  // wlds fragment order: slot(jh, cm, lane) = jh*4096 + cm*64 + lane (8 bf16 each):
  // holds W row j = jh*16+(lane&15), k = cm*32 + (lane>>4)*8 .. +8
  // -> every ds_read_b128 is lane-linear (zero bank conflicts)
  __shared__ unsigned short wlds[65536];   // 128 KiB
  __shared__ float glds[32 * 36];
  __shared__ float bias[32];

  const int tid   = threadIdx.x;
  const int layer = blockIdx.x >> 7;
  const int wg    = blockIdx.x & 127;
  const int h0    = wg * 8;
  // sub-counter layout: cnt[layer][t][sub], sub-stride 16 dwords (64B line)
  unsigned* cnt1  = flags;                  // layer-0: 512 steps x 8 subs x 16
  unsigned* cnt2  = flags + 512 * 128;      // layer-1
  unsigned* mycnt = layer ? cnt2 : cnt1;
  const int mysub = (wg & 7) * 16;

  // one-time: W slice (32 rows x 2048 f32, coalesced reads) -> fragment-ordered bf16 LDS
  for (int it = 0; it < 32; ++it) {
    int e = (it * 256 + tid) * 8;
    int r = e >> 11;                       // local row: gate = r>>3, i = r&7
    int k = e & 2047;
    const float* src = W + (((size_t)layer * 4 + (r >> 3)) * HH + (h0 + (r & 7))) * (size_t)KTOT + k;
    int slot = ((r >> 4) << 12) + (((k >> 8) * 8 + ((k >> 5) & 7)) << 6) + (r & 15) + (((k >> 3) & 3) << 4);
    *(us8*)&wlds[(unsigned)slot * 8] = pack8(*(const f4*)src, *(const f4*)(src + 4));
  }
  if (tid < 32) bias[tid] = Bb[((size_t)layer * 4 + (tid >> 3)) * HH + h0 + (tid & 7)];
  __syncthreads();

  const int lane = tid & 63;
  const int wid  = tid >> 6;
  const int nh = wid >> 1, jh = wid & 1;
  const int arow  = nh * 16 + (lane & 15);     // batch row for A fragments
  const int rbase = (lane >> 4) * 8;           // k-slice within 32-wide K step
  const unsigned short* wbase = &wlds[((unsigned)(jh * 4096 + lane)) * 8u];

  float lng = 0.f;                             // cell state (n=tid>>3, h=h0+(tid&7))

  for (int t = 0; t < LL; ++t) {
    us8 nf[4][8], rf[4][8];
    f4 acc = {0.f, 0.f, 0.f, 0.f};

    // ---------- "now" half (flag-free for layer 0; cnt1[t] for layer 1) ----------
    if (layer == 0) {
      if (x0) {
        const unsigned short* nsrc = x0 + ((size_t)t * NB + arow) * HH + rbase;
        #pragma unroll
        for (int c = 0; c < 4; ++c)
          #pragma unroll
          for (int m = 0; m < 8; ++m)
            nf[c][m] = *(const us8*)(nsrc + c * 256 + m * 32);
      } else {
        const float* nsrc = emb + (size_t)tokens[arow * LL + t] * HH + rbase;
        #pragma unroll
        for (int c = 0; c < 4; ++c)
          #pragma unroll
          for (int m = 0; m < 8; ++m)
            nf[c][m] = pack8(*(const f4*)(nsrc + c * 256 + m * 32),
                             *(const f4*)(nsrc + c * 256 + m * 32 + 4));
      }
    } else {
      waitsubs(cnt1 + (size_t)t * 128, 16);
      const unsigned short* nsrc = s1 + ((size_t)t * NB + arow) * HH + rbase;
      #pragma unroll
      for (int c = 0; c < 4; ++c)
        #pragma unroll
        for (int m = 0; m < 8; ++m)
          nf[c][m] = *(const us8*)(nsrc + c * 256 + m * 32);
    }
    #pragma unroll
    for (int c = 0; c < 4; ++c)
      #pragma unroll
      for (int m = 0; m < 8; ++m)
        acc = __builtin_amdgcn_mfma_f32_16x16x32_bf16(
                __builtin_bit_cast(bf8, nf[c][m]),
                __builtin_bit_cast(bf8, *(const us8*)(wbase + ((4 + c) * 8 + m) * 512)),
                acc, 0, 0, 0);

    // ---------- recurrent half (own layer's previous step) ----------
    if (t > 0) {
      waitsubs(mycnt + (size_t)(t - 1) * 128, 16);
      if (layer == 0) {
        const unsigned short* rsrc = s1 + ((size_t)(t - 1) * NB + arow) * HH + rbase;
        #pragma unroll
        for (int c = 0; c < 4; ++c)
          #pragma unroll
          for (int m = 0; m < 8; ++m)
            rf[c][m] = *(const us8*)(rsrc + c * 256 + m * 32);
      } else if (s2) {
        const unsigned short* rsrc = s2 + ((size_t)(t - 1) * NB + arow) * HH + rbase;
        #pragma unroll
        for (int c = 0; c < 4; ++c)
          #pragma unroll
          for (int m = 0; m < 8; ++m)
            rf[c][m] = *(const us8*)(rsrc + c * 256 + m * 32);
      } else {
        const float* rsrc = out + ((size_t)arow * LL + (t - 1)) * HH + rbase;
        #pragma unroll
        for (int c = 0; c < 4; ++c)
          #pragma unroll
          for (int m = 0; m < 8; ++m)
            rf[c][m] = pack8(*(const f4*)(rsrc + c * 256 + m * 32),
                             *(const f4*)(rsrc + c * 256 + m * 32 + 4));
      }
      #pragma unroll
      for (int c = 0; c < 4; ++c)
        #pragma unroll
        for (int m = 0; m < 8; ++m)
          acc = __builtin_amdgcn_mfma_f32_16x16x32_bf16(
                  __builtin_bit_cast(bf8, rf[c][m]),
                  __builtin_bit_cast(bf8, *(const us8*)(wbase + (c * 8 + m) * 512)),
                  acc, 0, 0, 0);
    }

    // ---------- scatter gates (C/D: col=lane&15, row=(lane>>4)*4+reg) ----------
    {
      int grow = nh * 16 + ((lane >> 4) << 2);
      int gcol = jh * 16 + (lane & 15);
      glds[(grow + 0) * 36 + gcol] = acc[0];
      glds[(grow + 1) * 36 + gcol] = acc[1];
      glds[(grow + 2) * 36 + gcol] = acc[2];
      glds[(grow + 3) * 36 + gcol] = acc[3];
    }
    __syncthreads();

    // ---------- state update: thread owns (n=tid>>3, i=tid&7); gates f,i,o,cand ----------
    {
      int n = tid >> 3, i = tid & 7;
      float gf = glds[n * 36 +  0 + i] + bias[ 0 + i];
      float gi = glds[n * 36 +  8 + i] + bias[ 8 + i];
      float go = glds[n * 36 + 16 + i] + bias[16 + i];
      float gc = glds[n * 36 + 24 + i] + bias[24 + i];
      float fg = 1.f / (1.f + __expf(-gf));
      float ig = 1.f / (1.f + __expf(-gi));
      float og = 1.f / (1.f + __expf(-go));
      lng = fg * lng + ig * gc;                     // cand raw (matches reference)
      float a  = fabsf(lng);
      float e  = __expf(-2.f * a);
      float th = __builtin_copysignf((1.f - e) / (1.f + e), lng);
      float sh = og * th;

      // bf16 value + neighbor's (i,i+1 adjacent threads, same wave) -> aligned u32
      unsigned v16 = f2bf(sh);
      unsigned nb  = __shfl_down(v16, 1);
      unsigned pair = v16 | (nb << 16);

      if (layer == 0) {
        if (!(i & 1))
          stwt((unsigned*)(s1 + ((size_t)t * NB + n) * HH + h0 + i), pair);
      } else {
        stwt((unsigned*)(out + ((size_t)n * LL + t) * HH + h0 + i),
             __builtin_bit_cast(unsigned, sh));
        if (s2 && !(i & 1))
          stwt((unsigned*)(s2 + ((size_t)t * NB + n) * HH + h0 + i), pair);
      }
    }
    __syncthreads();   // vmcnt(0) per wave: all write-through stores accepted
    if (tid == 0)
      __hip_atomic_fetch_add(mycnt + (size_t)t * 128 + mysub, 1u,
                             __ATOMIC_RELEASE, __HIP_MEMORY_SCOPE_AGENT);
  }
}

extern "C" void kernel_launch(void* const* d_in, const int* in_sizes, int n_in,
                              void* d_out, int out_size, void* d_ws, size_t ws_size,
                              hipStream_t stream) {
  const int*   tokens = (const int*)d_in[0];
  const float* emb    = (const float*)d_in[1];
  const float* W      = (const float*)d_in[2];
  const float* Bb     = (const float*)d_in[3];
  float*       out    = (float*)d_out;

  // ws layout:
  //   [0, 512KB)    sub-counters: cnt[2][512][8] on separate 64B lines
  //   [512KB,+32MB) s1 bf16 [512][32][1024]                    (required)
  //   optional s2 (layer-1 bf16 state), optional x0 (prepacked emb)
  const size_t FL = 524288;
  const size_t SZ = (size_t)LL * NB * HH * sizeof(unsigned short);   // 32 MiB
  unsigned*       flags = (unsigned*)d_ws;
  unsigned short* s1    = (unsigned short*)((char*)d_ws + FL);
  unsigned short* s2    = (ws_size >= FL + 2 * SZ) ? (unsigned short*)((char*)d_ws + FL + SZ) : nullptr;
  unsigned short* x0    = (ws_size >= FL + 3 * SZ) ? (unsigned short*)((char*)d_ws + FL + 2 * SZ) : nullptr;

  hipMemsetAsync(d_ws, 0, FL, stream);   // zero counters every replay (graph-captured)
  if (x0) prepack<<<dim3(8192), dim3(256), 0, stream>>>(tokens, emb, x0);

  void* args[] = { (void*)&tokens, (void*)&emb, (void*)&W, (void*)&Bb,
                   (void*)&out, (void*)&flags, (void*)&s1, (void*)&s2, (void*)&x0 };
  hipLaunchCooperativeKernel((void*)lstm_persist, dim3(256), dim3(256), args, 0, stream);
}